// Round 4
// baseline (236.998 us; speedup 1.0000x reference)
//
#include <hip/hip_runtime.h>

// CapsuleFC: B=64, N=128, A=64, M=128, D=64
// out = [ncv (B*M*D) | na (B*M) | qk (B*N*M)], fp32
typedef __attribute__((ext_vector_type(8))) short bf16x8;
typedef __attribute__((ext_vector_type(4))) float f32x4;

constexpr int Bq = 64, Nq = 128, Aq = 64, Mq = 128, Dq = 64;
constexpr int MD = Mq * Dq;    // 8192
constexpr int NM = Nq * Mq;    // 16384
constexpr int NA = Nq * Aq;    // 8192
constexpr int NCV_SZ = Bq * MD;   // 524288
constexpr int NA_SZ  = Bq * Mq;   // 8192
constexpr float SCALE = 0.125f;   // 1/sqrt(64)

__device__ __forceinline__ unsigned short f2b(float f) {  // fp32 -> bf16 RNE
  unsigned u = __float_as_uint(f);
  return (unsigned short)((u + 0x7fffu + ((u >> 16) & 1u)) >> 16);
}
__device__ __forceinline__ unsigned cvt2(float lo, float hi) {
  return ((unsigned)f2b(hi) << 16) | (unsigned)f2b(lo);
}
__device__ __forceinline__ bf16x8 pack8(const float* v) {
  union { unsigned u[4]; bf16x8 b; } x;
  x.u[0] = cvt2(v[0], v[1]); x.u[1] = cvt2(v[2], v[3]);
  x.u[2] = cvt2(v[4], v[5]); x.u[3] = cvt2(v[6], v[7]);
  return x.b;
}
// async global->LDS DMA, 16B per lane; LDS dst = uniform base + lane*16
__device__ __forceinline__ void dma16(const float* g, float* l) {
  __builtin_amdgcn_global_load_lds(
      (const __attribute__((address_space(1))) unsigned*)g,
      (__attribute__((address_space(3))) unsigned*)l, 16, 0, 0);
}

// ---------------- init: ncv = 0, na = 1 ----------------
__global__ __launch_bounds__(256) void k0_init(float* __restrict__ out) {
  int i = blockIdx.x * 256 + threadIdx.x;
  if (i < NCV_SZ) out[i] = 0.0f;
  else if (i < NCV_SZ + NA_SZ) out[i] = 1.0f;
}

// ---------------- K1: logits via MFMA, 2-phase DMA-pipelined w stream ----------------
// grid (mc=32, ns=16), block 256 (4 waves). Block: 8 n's at fixed mc (4 m's).
// LDS: double-buffered fp32 W half-tiles [32k][256c] (32 KB x2).
// Source XOR-swizzle ((row>>3)&1)<<6 bytes; same XOR on read -> 2-way (free).
__global__ __launch_bounds__(256) void k1_logits(
    const float* __restrict__ input,   // [B,N,A]
    const float* __restrict__ ncvin,   // [B,M,D]
    const float* __restrict__ wgt,     // [N,A,M,D]
    float* __restrict__ logits) {      // [B,N,M] (qk region)
  const int mc = blockIdx.x;
  const int n0 = blockIdx.y * 8;
  const int t  = threadIdx.x;
  const int wv = t >> 6, l = t & 63;
  const int lr = l & 15, g = l >> 4;
  const int m  = mc * 4 + wv;

  __shared__ float Wf[2][32 * 256];   // 64 KB

  auto stage = [&](int hh) {
    const int nn = n0 + (hh >> 1);
    const int ks = (hh & 1) * 32;
    float* dst = &Wf[hh & 1][0];
#pragma unroll
    for (int rr = 0; rr < 8; ++rr) {
      const int al = wv * 8 + rr;
      const char* gs = (const char*)(wgt + (size_t)(nn * Aq + ks + al) * MD + mc * 256)
                       + ((l * 16) ^ (((al >> 3) & 1) << 6));
      dma16((const float*)gs, dst + al * 256);
    }
  };

  stage(0);
  f32x4 acc[4][4];

  for (int h = 0; h < 16; ++h) {
    const int nn = n0 + (h >> 1);
    const int ks = (h & 1) * 32;

    // A fragments straight from global (input is L2-resident)
    float av[4][8];
#pragma unroll
    for (int i = 0; i < 4; ++i) {
      const float* ap = input + (size_t)(16 * i + lr) * NA + nn * Aq + ks + g * 8;
      *(float4*)&av[i][0] = *(const float4*)ap;
      *(float4*)&av[i][4] = *(const float4*)(ap + 4);
    }

    if (h < 15) {
      stage(h + 1);
      asm volatile("s_waitcnt vmcnt(8)" ::: "memory");  // drain stage-h (+A); keep h+1 in flight
    } else {
      asm volatile("s_waitcnt vmcnt(0)" ::: "memory");
    }
    __builtin_amdgcn_s_barrier();

    if ((h & 1) == 0) {
#pragma unroll
      for (int i = 0; i < 4; ++i)
#pragma unroll
        for (int j = 0; j < 4; ++j) acc[i][j] = (f32x4)(0.0f);
    }

    bf16x8 af[4];
#pragma unroll
    for (int i = 0; i < 4; ++i) af[i] = pack8(av[i]);

    const float* bufp = &Wf[h & 1][0];
#pragma unroll
    for (int j = 0; j < 4; ++j) {
      const int c  = 64 * wv + 16 * j + lr;
      const int cx = c ^ ((g & 1) << 4);
      float bv[8];
#pragma unroll
      for (int e = 0; e < 8; ++e) bv[e] = bufp[(g * 8 + e) * 256 + cx];
      bf16x8 bf = pack8(bv);
#pragma unroll
      for (int i = 0; i < 4; ++i)
        acc[i][j] = __builtin_amdgcn_mfma_f32_16x16x32_bf16(af[i], bf, acc[i][j], 0, 0, 0);
    }
    __builtin_amdgcn_s_barrier();   // all waves done reading buf[h&1]

    if (h & 1) {
      // epilogue for nn: logits[b,nn,m] = SCALE * sum_d votes[b,d]*ncvin[b,m,d]
      float lp[4][4];
#pragma unroll
      for (int i = 0; i < 4; ++i)
#pragma unroll
        for (int r = 0; r < 4; ++r) lp[i][r] = 0.0f;
#pragma unroll
      for (int i = 0; i < 4; ++i)
#pragma unroll
        for (int j = 0; j < 4; ++j) {
          const int d = 16 * j + lr;
#pragma unroll
          for (int r = 0; r < 4; ++r) {
            const int b = 16 * i + 4 * g + r;
            lp[i][r] = fmaf(acc[i][j][r], ncvin[(size_t)b * MD + m * Dq + d], lp[i][r]);
          }
        }
#pragma unroll
      for (int off = 1; off < 16; off <<= 1)
#pragma unroll
        for (int i = 0; i < 4; ++i)
#pragma unroll
          for (int r = 0; r < 4; ++r) lp[i][r] += __shfl_xor(lp[i][r], off);
#pragma unroll
      for (int i = 0; i < 4; ++i)
#pragma unroll
        for (int r = 0; r < 4; ++r)
          if (lr == i * 4 + r) {
            const int b = 16 * i + 4 * g + r;
            logits[(size_t)b * NM + (size_t)nn * Mq + m] = SCALE * lp[i][r];
          }
    }
  }
}

// ---------------- K2: softmax + act modulation + renorm (in place) ----------------
__global__ __launch_bounds__(256) void k2_softmax(
    const float* __restrict__ next_act,  // [B,M]
    float* __restrict__ qk) {            // [B,N,M] in/out
  const int row  = blockIdx.x * 4 + (threadIdx.x >> 6);  // b*N + n
  const int lane = threadIdx.x & 63;
  const int b = row >> 7;
  float* p = qk + (size_t)row * Mq;
  float x0 = p[lane], x1 = p[lane + 64];
  float mx = fmaxf(x0, x1);
#pragma unroll
  for (int off = 32; off; off >>= 1) mx = fmaxf(mx, __shfl_xor(mx, off));
  float e0 = __expf(x0 - mx), e1 = __expf(x1 - mx);
  float s = e0 + e1;
#pragma unroll
  for (int off = 32; off; off >>= 1) s += __shfl_xor(s, off);
  float a0 = next_act[b * Mq + lane], a1 = next_act[b * Mq + lane + 64];
  float t0 = (e0 / s) * a0, t1 = (e1 / s) * a1;
  float s2 = t0 + t1;
#pragma unroll
  for (int off = 32; off; off >>= 1) s2 += __shfl_xor(s2, off);
  s2 += 1e-10f;
  p[lane]      = t0 / s2;
  p[lane + 64] = t1 / s2;
}

// ---------------- K3: aggregation via MFMA, same 2-phase stream ----------------
// ncv[b,m,d] = sum_{n,a} (input[b,n,a]*qk[b,n,m]*act[b,n]) * w[n,a,m,d]
// grid (mc=32, ns=16), block 256; 8 n's per block, acc over all, one atomic epilogue.
__global__ __launch_bounds__(256) void k3_aggregate(
    const float* __restrict__ input,     // [B,N,A]
    const float* __restrict__ cur_act,   // [B,N]
    const float* __restrict__ wgt,       // [N,A,M,D]
    const float* __restrict__ qk,        // [B,N,M] (final)
    float* __restrict__ ncv) {           // [B,M,D], pre-zeroed
  const int mc = blockIdx.x;
  const int n0 = blockIdx.y * 8;
  const int t  = threadIdx.x;
  const int wv = t >> 6, l = t & 63;
  const int lr = l & 15, g = l >> 4;
  const int m  = mc * 4 + wv;

  __shared__ float Wf[2][32 * 256];   // 64 KB

  auto stage = [&](int hh) {
    const int nn = n0 + (hh >> 1);
    const int ks = (hh & 1) * 32;
    float* dst = &Wf[hh & 1][0];
#pragma unroll
    for (int rr = 0; rr < 8; ++rr) {
      const int al = wv * 8 + rr;
      const char* gs = (const char*)(wgt + (size_t)(nn * Aq + ks + al) * MD + mc * 256)
                       + ((l * 16) ^ (((al >> 3) & 1) << 6));
      dma16((const float*)gs, dst + al * 256);
    }
  };

  stage(0);
  f32x4 acc[4][4];
#pragma unroll
  for (int i = 0; i < 4; ++i)
#pragma unroll
    for (int j = 0; j < 4; ++j) acc[i][j] = (f32x4)(0.0f);

  float zr[4];
  for (int h = 0; h < 16; ++h) {
    const int nn = n0 + (h >> 1);
    const int ks = (h & 1) * 32;

    float qv[4], cv[4];
    if ((h & 1) == 0) {
#pragma unroll
      for (int i = 0; i < 4; ++i) {
        const int b = 16 * i + lr;
        qv[i] = qk[(size_t)b * NM + (size_t)nn * Mq + m];
        cv[i] = cur_act[b * Nq + nn];
      }
    }

    float av[4][8];
#pragma unroll
    for (int i = 0; i < 4; ++i) {
      const float* ap = input + (size_t)(16 * i + lr) * NA + nn * Aq + ks + g * 8;
      *(float4*)&av[i][0] = *(const float4*)ap;
      *(float4*)&av[i][4] = *(const float4*)(ap + 4);
    }

    if (h < 15) {
      stage(h + 1);
      asm volatile("s_waitcnt vmcnt(8)" ::: "memory");
    } else {
      asm volatile("s_waitcnt vmcnt(0)" ::: "memory");
    }
    __builtin_amdgcn_s_barrier();

    if ((h & 1) == 0) {
#pragma unroll
      for (int i = 0; i < 4; ++i) zr[i] = qv[i] * cv[i];
    }

    bf16x8 af[4];
#pragma unroll
    for (int i = 0; i < 4; ++i) {
      float sv[8];
#pragma unroll
      for (int e = 0; e < 8; ++e) sv[e] = av[i][e] * zr[i];
      af[i] = pack8(sv);
    }

    const float* bufp = &Wf[h & 1][0];
#pragma unroll
    for (int j = 0; j < 4; ++j) {
      const int c  = 64 * wv + 16 * j + lr;
      const int cx = c ^ ((g & 1) << 4);
      float bv[8];
#pragma unroll
      for (int e = 0; e < 8; ++e) bv[e] = bufp[(g * 8 + e) * 256 + cx];
      bf16x8 bf = pack8(bv);
#pragma unroll
      for (int i = 0; i < 4; ++i)
        acc[i][j] = __builtin_amdgcn_mfma_f32_16x16x32_bf16(af[i], bf, acc[i][j], 0, 0, 0);
    }
    __builtin_amdgcn_s_barrier();
  }

  // epilogue: atomic partial sums over the 16 n-split blocks
#pragma unroll
  for (int i = 0; i < 4; ++i)
#pragma unroll
    for (int j = 0; j < 4; ++j) {
      const int d = 16 * j + lr;
#pragma unroll
      for (int r = 0; r < 4; ++r) {
        const int b = 16 * i + 4 * g + r;
        atomicAdd(&ncv[(size_t)b * MD + m * Dq + d], acc[i][j][r]);
      }
    }
}

extern "C" void kernel_launch(void* const* d_in, const int* in_sizes, int n_in,
                              void* d_out, int out_size, void* d_ws, size_t ws_size,
                              hipStream_t stream) {
  const float* input    = (const float*)d_in[0];
  const float* cur_act  = (const float*)d_in[1];
  const float* ncvin    = (const float*)d_in[2];
  const float* next_act = (const float*)d_in[3];
  const float* wgt      = (const float*)d_in[4];
  // d_in[5] = num_iter (unused by reference)

  float* out = (float*)d_out;
  float* ncv = out;
  float* qk  = out + NCV_SZ + NA_SZ;

  k0_init<<<(NCV_SZ + NA_SZ + 255) / 256, 256, 0, stream>>>(out);
  k1_logits<<<dim3(32, 16), 256, 0, stream>>>(input, ncvin, wgt, qk);
  k2_softmax<<<(Bq * Nq) / 4, 256, 0, stream>>>(next_act, qk);
  k3_aggregate<<<dim3(32, 16), 256, 0, stream>>>(input, cur_act, wgt, qk, ncv);
}

// Round 5
// 161.329 us; speedup vs baseline: 1.4690x; 1.4690x over previous
//
#include <hip/hip_runtime.h>

// CapsuleFC: B=64, N=128, A=64, M=128, D=64
// out = [ncv (B*M*D) | na (B*M) | qk (B*N*M)], fp32
typedef __attribute__((ext_vector_type(8))) short bf16x8;
typedef __attribute__((ext_vector_type(4))) float f32x4;

constexpr int Bq = 64, Nq = 128, Aq = 64, Mq = 128, Dq = 64;
constexpr int MD = Mq * Dq;    // 8192
constexpr int NM = Nq * Mq;    // 16384
constexpr int NA = Nq * Aq;    // 8192
constexpr int NCV_SZ = Bq * MD;   // 524288
constexpr int NA_SZ  = Bq * Mq;   // 8192
constexpr float SCALE = 0.125f;   // 1/sqrt(64)

__device__ __forceinline__ unsigned short f2b(float f) {  // fp32 -> bf16 RNE
  unsigned u = __float_as_uint(f);
  return (unsigned short)((u + 0x7fffu + ((u >> 16) & 1u)) >> 16);
}
__device__ __forceinline__ unsigned cvt2(float lo, float hi) {
  return ((unsigned)f2b(hi) << 16) | (unsigned)f2b(lo);
}
__device__ __forceinline__ bf16x8 pack8(const float* v) {
  union { unsigned u[4]; bf16x8 b; } x;
  x.u[0] = cvt2(v[0], v[1]); x.u[1] = cvt2(v[2], v[3]);
  x.u[2] = cvt2(v[4], v[5]); x.u[3] = cvt2(v[6], v[7]);
  return x.b;
}
// async global->LDS DMA, 16B per lane; LDS dst = uniform base + lane*16
__device__ __forceinline__ void dma16(const float* g, float* l) {
  __builtin_amdgcn_global_load_lds(
      (const __attribute__((address_space(1))) unsigned*)g,
      (__attribute__((address_space(3))) unsigned*)l, 16, 0, 0);
}

// ---------------- init: ncv = 0, na = 1 ----------------
__global__ __launch_bounds__(256) void k0_init(float* __restrict__ out) {
  int i = blockIdx.x * 256 + threadIdx.x;
  if (i < NCV_SZ) out[i] = 0.0f;
  else if (i < NCV_SZ + NA_SZ) out[i] = 1.0f;
}

// ---------------- K1: logits via MFMA, 2-phase DMA-pipelined w stream ----------------
// grid (mc=32, ns=16), block 256 (4 waves; wave wv owns m = mc*4+wv).
// Tiles walked DESCENDING (L3-cyclic with k3's ascending walk).
// NO global loads inside the K-loop except av (pinned) and the DMA prefetch.
__global__ __launch_bounds__(256, 2) void k1_logits(
    const float* __restrict__ input,   // [B,N,A]
    const float* __restrict__ ncvin,   // [B,M,D]
    const float* __restrict__ wgt,     // [N,A,M,D]
    float* __restrict__ logits) {      // [B,N,M] (qk region)
  const int mc = blockIdx.x;
  const int n0 = blockIdx.y * 8;
  const int t  = threadIdx.x;
  const int wv = t >> 6, l = t & 63;
  const int lr = l & 15, g = l >> 4;
  const int m  = mc * 4 + wv;

  __shared__ float Wf[2][32 * 256];   // 64 KB

  // preload ncvin fragment into registers (once; epilogue is then vmcnt-free)
  float cnv[4][4][4];
#pragma unroll
  for (int i = 0; i < 4; ++i)
#pragma unroll
    for (int j = 0; j < 4; ++j)
#pragma unroll
      for (int r = 0; r < 4; ++r)
        cnv[i][j][r] = ncvin[(size_t)(16 * i + 4 * g + r) * MD + m * Dq + 16 * j + lr];

  auto stage = [&](int h) {            // h = logical step 0..15, descending walk
    const int hh = 15 - h;
    const int nn = n0 + (hh >> 1);
    const int ks = (hh & 1) * 32;
    float* dst = &Wf[h & 1][0];
#pragma unroll
    for (int rr = 0; rr < 8; ++rr) {
      const int al = wv * 8 + rr;
      const char* gs = (const char*)(wgt + (size_t)(nn * Aq + ks + al) * MD + mc * 256)
                       + ((l * 16) ^ (((al >> 3) & 1) << 6));
      dma16((const float*)gs, dst + al * 256);
    }
  };

  stage(0);
  f32x4 acc[4][4];

  for (int h = 0; h < 16; ++h) {
    const int hh = 15 - h;
    const int nn = n0 + (hh >> 1);
    const int ks = (hh & 1) * 32;

    // A fragments straight from global (input is L2-resident); pinned before DMAs
    float av[4][8];
#pragma unroll
    for (int i = 0; i < 4; ++i) {
      const float* ap = input + (size_t)(16 * i + lr) * NA + nn * Aq + ks + g * 8;
      *(float4*)&av[i][0] = *(const float4*)ap;
      *(float4*)&av[i][4] = *(const float4*)(ap + 4);
    }
    __builtin_amdgcn_sched_barrier(0);

    if (h < 15) {
      stage(h + 1);
      asm volatile("s_waitcnt vmcnt(8)" ::: "memory");  // drain tile h + av; keep h+1 in flight
    } else {
      asm volatile("s_waitcnt vmcnt(0)" ::: "memory");
    }
    __builtin_amdgcn_s_barrier();

    if ((h & 1) == 0) {
#pragma unroll
      for (int i = 0; i < 4; ++i)
#pragma unroll
        for (int j = 0; j < 4; ++j) acc[i][j] = (f32x4)(0.0f);
    }

    bf16x8 af[4];
#pragma unroll
    for (int i = 0; i < 4; ++i) af[i] = pack8(av[i]);

    const float* bufp = &Wf[h & 1][0];
#pragma unroll
    for (int j = 0; j < 4; ++j) {
      const int c  = 64 * wv + 16 * j + lr;
      const int cx = c ^ ((g & 1) << 4);
      float bv[8];
#pragma unroll
      for (int e = 0; e < 8; ++e) bv[e] = bufp[(g * 8 + e) * 256 + cx];
      bf16x8 bf = pack8(bv);
#pragma unroll
      for (int i = 0; i < 4; ++i)
        acc[i][j] = __builtin_amdgcn_mfma_f32_16x16x32_bf16(af[i], bf, acc[i][j], 0, 0, 0);
    }
    __builtin_amdgcn_s_barrier();   // all waves done reading buf[h&1]

    if (h & 1) {
      // epilogue (register-only + shfl + ONE store): logits[b,nn,m]
      float lp[4][4];
#pragma unroll
      for (int i = 0; i < 4; ++i)
#pragma unroll
        for (int r = 0; r < 4; ++r) lp[i][r] = 0.0f;
#pragma unroll
      for (int i = 0; i < 4; ++i)
#pragma unroll
        for (int j = 0; j < 4; ++j)
#pragma unroll
          for (int r = 0; r < 4; ++r)
            lp[i][r] = fmaf(acc[i][j][r], cnv[i][j][r], lp[i][r]);
#pragma unroll
      for (int off = 1; off < 16; off <<= 1)
#pragma unroll
        for (int i = 0; i < 4; ++i)
#pragma unroll
          for (int r = 0; r < 4; ++r) lp[i][r] += __shfl_xor(lp[i][r], off);
      // lane (g,lr) stores b = 16*(lr>>2) + 4*g + (lr&3); select lp by lr (static idx)
      float ov = lp[0][0];
#pragma unroll
      for (int i = 0; i < 4; ++i)
#pragma unroll
        for (int r = 0; r < 4; ++r)
          ov = (lr == i * 4 + r) ? lp[i][r] : ov;
      const int b = 16 * (lr >> 2) + 4 * g + (lr & 3);
      logits[(size_t)b * NM + (size_t)nn * Mq + m] = SCALE * ov;
    }
  }
}

// ---------------- K2: softmax + act modulation + renorm (in place) ----------------
__global__ __launch_bounds__(256) void k2_softmax(
    const float* __restrict__ next_act,  // [B,M]
    float* __restrict__ qk) {            // [B,N,M] in/out
  const int row  = blockIdx.x * 4 + (threadIdx.x >> 6);  // b*N + n
  const int lane = threadIdx.x & 63;
  const int b = row >> 7;
  float* p = qk + (size_t)row * Mq;
  float x0 = p[lane], x1 = p[lane + 64];
  float mx = fmaxf(x0, x1);
#pragma unroll
  for (int off = 32; off; off >>= 1) mx = fmaxf(mx, __shfl_xor(mx, off));
  float e0 = __expf(x0 - mx), e1 = __expf(x1 - mx);
  float s = e0 + e1;
#pragma unroll
  for (int off = 32; off; off >>= 1) s += __shfl_xor(s, off);
  float a0 = next_act[b * Mq + lane], a1 = next_act[b * Mq + lane + 64];
  float t0 = (e0 / s) * a0, t1 = (e1 / s) * a1;
  float s2 = t0 + t1;
#pragma unroll
  for (int off = 32; off; off >>= 1) s2 += __shfl_xor(s2, off);
  s2 += 1e-10f;
  p[lane]      = t0 / s2;
  p[lane + 64] = t1 / s2;
}

// ---------------- K3: aggregation via MFMA, same 2-phase stream (ascending walk) ----
// ncv[b,m,d] = sum_{n,a} (input[b,n,a]*z[b,n,m]) * w[n,a,m,d], z = qk*cur_act
__global__ __launch_bounds__(256, 2) void k3_aggregate(
    const float* __restrict__ input,     // [B,N,A]
    const float* __restrict__ cur_act,   // [B,N]
    const float* __restrict__ wgt,       // [N,A,M,D]
    const float* __restrict__ qk,        // [B,N,M] (final)
    float* __restrict__ ncv) {           // [B,M,D], pre-zeroed
  const int mc = blockIdx.x;
  const int n0 = blockIdx.y * 8;
  const int t  = threadIdx.x;
  const int wv = t >> 6, l = t & 63;
  const int lr = l & 15, g = l >> 4;
  const int m  = mc * 4 + wv;

  __shared__ float Wf[2][32 * 256];   // 64 KB
  __shared__ float zl[8][4][64];      // [nn][mm][b], 8 KB, persistent

  // pre-stage z = qk*cur_act (coalesced float4 over the 4 m's), once
#pragma unroll
  for (int p = 0; p < 2; ++p) {
    const int idx = t + p * 256;             // 512 (b,nn) pairs
    const int b = idx >> 3, nn = idx & 7;
    float4 q4 = *(const float4*)&qk[(size_t)b * NM + (size_t)(n0 + nn) * Mq + mc * 4];
    float ca = cur_act[b * Nq + n0 + nn];
    zl[nn][0][b] = q4.x * ca; zl[nn][1][b] = q4.y * ca;
    zl[nn][2][b] = q4.z * ca; zl[nn][3][b] = q4.w * ca;
  }
  __syncthreads();                     // z visible to all waves (before any DMA)

  auto stage = [&](int h) {            // ascending walk
    const int nn = n0 + (h >> 1);
    const int ks = (h & 1) * 32;
    float* dst = &Wf[h & 1][0];
#pragma unroll
    for (int rr = 0; rr < 8; ++rr) {
      const int al = wv * 8 + rr;
      const char* gs = (const char*)(wgt + (size_t)(nn * Aq + ks + al) * MD + mc * 256)
                       + ((l * 16) ^ (((al >> 3) & 1) << 6));
      dma16((const float*)gs, dst + al * 256);
    }
  };

  stage(0);
  f32x4 acc[4][4];
#pragma unroll
  for (int i = 0; i < 4; ++i)
#pragma unroll
    for (int j = 0; j < 4; ++j) acc[i][j] = (f32x4)(0.0f);

  float zr[4];
  for (int h = 0; h < 16; ++h) {
    const int nnl = h >> 1;
    const int nn  = n0 + nnl;
    const int ks  = (h & 1) * 32;

    if ((h & 1) == 0) {
#pragma unroll
      for (int i = 0; i < 4; ++i) zr[i] = zl[nnl][wv][16 * i + lr];   // ds_read, no vmcnt
    }

    float av[4][8];
#pragma unroll
    for (int i = 0; i < 4; ++i) {
      const float* ap = input + (size_t)(16 * i + lr) * NA + nn * Aq + ks + g * 8;
      *(float4*)&av[i][0] = *(const float4*)ap;
      *(float4*)&av[i][4] = *(const float4*)(ap + 4);
    }
    __builtin_amdgcn_sched_barrier(0);

    if (h < 15) {
      stage(h + 1);
      asm volatile("s_waitcnt vmcnt(8)" ::: "memory");
    } else {
      asm volatile("s_waitcnt vmcnt(0)" ::: "memory");
    }
    __builtin_amdgcn_s_barrier();

    bf16x8 af[4];
#pragma unroll
    for (int i = 0; i < 4; ++i) {
      float sv[8];
#pragma unroll
      for (int e = 0; e < 8; ++e) sv[e] = av[i][e] * zr[i];
      af[i] = pack8(sv);
    }

    const float* bufp = &Wf[h & 1][0];
#pragma unroll
    for (int j = 0; j < 4; ++j) {
      const int c  = 64 * wv + 16 * j + lr;
      const int cx = c ^ ((g & 1) << 4);
      float bv[8];
#pragma unroll
      for (int e = 0; e < 8; ++e) bv[e] = bufp[(g * 8 + e) * 256 + cx];
      bf16x8 bf = pack8(bv);
#pragma unroll
      for (int i = 0; i < 4; ++i)
        acc[i][j] = __builtin_amdgcn_mfma_f32_16x16x32_bf16(af[i], bf, acc[i][j], 0, 0, 0);
    }
    __builtin_amdgcn_s_barrier();
  }

  // epilogue: atomic partial sums over the 16 n-split blocks
#pragma unroll
  for (int i = 0; i < 4; ++i)
#pragma unroll
    for (int j = 0; j < 4; ++j) {
      const int d = 16 * j + lr;
#pragma unroll
      for (int r = 0; r < 4; ++r) {
        const int b = 16 * i + 4 * g + r;
        atomicAdd(&ncv[(size_t)b * MD + m * Dq + d], acc[i][j][r]);
      }
    }
}

extern "C" void kernel_launch(void* const* d_in, const int* in_sizes, int n_in,
                              void* d_out, int out_size, void* d_ws, size_t ws_size,
                              hipStream_t stream) {
  const float* input    = (const float*)d_in[0];
  const float* cur_act  = (const float*)d_in[1];
  const float* ncvin    = (const float*)d_in[2];
  const float* next_act = (const float*)d_in[3];
  const float* wgt      = (const float*)d_in[4];
  // d_in[5] = num_iter (unused by reference)

  float* out = (float*)d_out;
  float* ncv = out;
  float* qk  = out + NCV_SZ + NA_SZ;

  k0_init<<<(NCV_SZ + NA_SZ + 255) / 256, 256, 0, stream>>>(out);
  k1_logits<<<dim3(32, 16), 256, 0, stream>>>(input, ncvin, wgt, qk);
  k2_softmax<<<(Bq * Nq) / 4, 256, 0, stream>>>(next_act, qk);
  k3_aggregate<<<dim3(32, 16), 256, 0, stream>>>(input, cur_act, wgt, qk, ncv);
}